// Round 12
// baseline (495.599 us; speedup 1.0000x reference)
//
#include <hip/hip_runtime.h>
#include <math.h>

#define Nn 50000
#define Ee 600000
#define Bg 128      // batches (graphs)
#define Hd 128      // hidden dim
#define Kt 30       // sortpool K
#define CO 32       // conv out channels
#define KW 5        // conv kernel
#define LOUT 26     // K - KW + 1
#define CAP 2048    // per-batch node cap for topk LDS (max real count ~460)
#define SCB 196     // ceil(50000/256) scan blocks

typedef float v2f __attribute__((ext_vector_type(2)));
typedef short bf16x8 __attribute__((ext_vector_type(8)));
typedef float f32x4 __attribute__((ext_vector_type(4)));

// bf16 round-to-nearest-even helpers (branchless, finite inputs)
__device__ __forceinline__ unsigned short bfr(float v) {
    unsigned u = __builtin_bit_cast(unsigned, v);
    unsigned r = (u + 0x7FFFu + ((u >> 16) & 1u)) >> 16;
    return (unsigned short)r;
}
__device__ __forceinline__ float bff(unsigned short h) {
    unsigned u = ((unsigned)h) << 16;
    return __builtin_bit_cast(float, u);
}

// ---------------- init + conv_w transpose + W 3-way split/pack ----------------
__global__ void initwprep_kernel(int* __restrict__ deg_i, int* __restrict__ cnt,
                            int* __restrict__ bstart,
                            const float* __restrict__ conv_w, float* __restrict__ wT2,
                            const float* __restrict__ W0, const float* __restrict__ W1,
                            const float* __restrict__ W2,
                            ushort* __restrict__ Bph, ushort* __restrict__ Bpm,
                            ushort* __restrict__ Bpl) {
    int i = blockIdx.x * 256 + threadIdx.x;
    if (i < Nn) { deg_i[i] = 1; cnt[i] = 0; }   // deg starts at 1 (self loop)
    if (i <= Bg) bstart[i] = Nn;                // sentinel
    if (i < CO * KW * Hd) {                     // wT2[o][k][ci] = conv_w[o][ci][k]
        int ci = i & 127;
        int r = i >> 7;          // o*KW + k
        int o = r / KW, k = r - o * KW;
        wT2[i] = conv_w[((size_t)o * Hd + ci) * KW + k];
    }
    if (i < 3 * 2048) {                          // W split+pack, B-fragment layout
        int l = i >> 11;
        int r = i & 2047;
        int kc = r >> 9;
        int n = (r >> 6) & 7;
        int lane = r & 63;
        int m = lane & 15, kq = lane >> 4;
        const float* W = (l == 0) ? W0 : (l == 1) ? W1 : W2;
        int col = n * 16 + m;
        size_t off = ((size_t)l * 2048 + (size_t)((kc * 8 + n) * 64 + lane)) * 8;
#pragma unroll
        for (int j = 0; j < 8; ++j) {
            float v = W[(size_t)(kc * 32 + kq * 8 + j) * Hd + col];
            unsigned short h = bfr(v);
            float r1 = v - bff(h);
            unsigned short mid = bfr(r1);
            Bph[off + j] = h;
            Bpm[off + j] = mid;
            Bpl[off + j] = bfr(r1 - bff(mid));
        }
    }
}

// ---------------- degree histogram + batch starts (boundary detect) ----------
__global__ void count_kernel(const int* __restrict__ ei, const int* __restrict__ batch,
                             int* __restrict__ deg_i, int* __restrict__ bstart) {
    int i = blockIdx.x * 256 + threadIdx.x;
    if (i < Ee) atomicAdd(&deg_i[ei[Ee + i]], 1);       // col = edge_index[1]
    if (i < Nn) {
        int b = batch[i];
        if (i == 0) {
            bstart[b] = 0;
        } else {
            int bp = batch[i - 1];
            if (bp != b) bstart[b] = i;
        }
    }
}

// ---------------- scan phase A: block sums of (deg-1), dinv ----------------
__global__ __launch_bounds__(256) void scanA_kernel(const int* __restrict__ deg_i,
                            float* __restrict__ dinv, int* __restrict__ bsum) {
    __shared__ int s[256];
    int tid = threadIdx.x;
    int i = blockIdx.x * 256 + tid;
    int v = 0;
    if (i < Nn) {
        int d = deg_i[i];
        dinv[i] = 1.0f / sqrtf((float)d);
        v = d - 1;
    }
    s[tid] = v;
    __syncthreads();
    for (int off = 128; off > 0; off >>= 1) {
        if (tid < off) s[tid] += s[tid + off];
        __syncthreads();
    }
    if (tid == 0) bsum[blockIdx.x] = s[0];
}

// ---------------- scan phase BC: redundant block-sum scan + local scan ------
// each block scans all 196 bsums in LDS (784 B) to get its own exclusive
// offset, then does the local inclusive scan -> row_ptr. Merges old B+C.
__global__ __launch_bounds__(256) void scanBC_kernel(const int* __restrict__ deg_i,
                            const int* __restrict__ bsum, int* __restrict__ row_ptr,
                            int* __restrict__ bstart) {
    __shared__ int ls[256];
    __shared__ int boffS;
    int tid = threadIdx.x;
    int v = (tid < SCB) ? bsum[tid] : 0;
    ls[tid] = v;
    __syncthreads();
    for (int off = 1; off < 256; off <<= 1) {
        int t = (tid >= off) ? ls[tid - off] : 0;
        __syncthreads();
        ls[tid] += t;
        __syncthreads();
    }
    if (tid == 0) boffS = (blockIdx.x > 0) ? ls[blockIdx.x - 1] : 0;
    __syncthreads();
    int boff = boffS;
    int i = blockIdx.x * 256 + tid;
    int v2 = (i < Nn) ? deg_i[i] - 1 : 0;
    ls[tid] = v2;
    __syncthreads();
    for (int off = 1; off < 256; off <<= 1) {
        int t = (tid >= off) ? ls[tid - off] : 0;
        __syncthreads();
        ls[tid] += t;
        __syncthreads();
    }
    if (i < Nn) row_ptr[i + 1] = ls[tid] + boff;
    if (i == 0) row_ptr[0] = 0;
    if (blockIdx.x == 0 && tid == 0) {   // empty batches inherit next start
        for (int b = Bg - 1; b >= 0; --b)
            if (bstart[b] == Nn) bstart[b] = bstart[b + 1];
    }
}

// ---------------- CSR fill (edges grouped by destination col) ----------------
__global__ void fill_kernel(const int* __restrict__ ei, const int* __restrict__ row_ptr,
                            int* __restrict__ cnt, int* __restrict__ csr_src) {
    int e = blockIdx.x * 256 + threadIdx.x;
    if (e >= Ee) return;
    int c = ei[Ee + e];
    int r = ei[e];
    int p = row_ptr[c] + atomicAdd(&cnt[c], 1);
    csr_src[p] = r;
}

// ---------------- MFMA matmul: hw[i] = dinv[i] * (Hin[i] @ W) ----------------
// 3-way split-bf16 (near-fp32). Retained products: a0b0,a1b0,a0b1,a1b1,a2b0,a0b2.
__global__ __launch_bounds__(256) void mmx_kernel(const float* __restrict__ Hin,
                            const ushort* __restrict__ Bph, const ushort* __restrict__ Bpm,
                            const ushort* __restrict__ Bpl,
                            const float* __restrict__ dinv, float* __restrict__ hw) {
    int tid = threadIdx.x;
    int w = tid >> 6, lane = tid & 63;
    int m = lane & 15, kq = lane >> 4;
    int rowA = blockIdx.x * 64 + w * 16 + m;
    bool va = rowA < Nn;
    const float* ap = Hin + (size_t)rowA * Hd;
    f32x4 acc[8];
#pragma unroll
    for (int n = 0; n < 8; ++n) acc[n] = (f32x4)0.f;
#pragma unroll
    for (int kc = 0; kc < 4; ++kc) {
        bf16x8 a0 = (bf16x8)0, a1 = (bf16x8)0, a2 = (bf16x8)0;
        if (va) {
            float av[8];
            *(float4*)&av[0] = *(const float4*)(ap + kc * 32 + kq * 8);
            *(float4*)&av[4] = *(const float4*)(ap + kc * 32 + kq * 8 + 4);
#pragma unroll
            for (int j = 0; j < 8; ++j) {
                unsigned short h = bfr(av[j]);
                float r1 = av[j] - bff(h);
                unsigned short mid = bfr(r1);
                a0[j] = (short)h;
                a1[j] = (short)mid;
                a2[j] = (short)bfr(r1 - bff(mid));
            }
        }
        const ushort* bhp = Bph + (size_t)((kc * 8) * 64 + lane) * 8;
        const ushort* bmp = Bpm + (size_t)((kc * 8) * 64 + lane) * 8;
        const ushort* blp = Bpl + (size_t)((kc * 8) * 64 + lane) * 8;
#pragma unroll
        for (int n = 0; n < 8; ++n) {
            bf16x8 b0 = *(const bf16x8*)(bhp + (size_t)n * 64 * 8);
            bf16x8 b1 = *(const bf16x8*)(bmp + (size_t)n * 64 * 8);
            bf16x8 b2 = *(const bf16x8*)(blp + (size_t)n * 64 * 8);
            acc[n] = __builtin_amdgcn_mfma_f32_16x16x32_bf16(a0, b0, acc[n], 0, 0, 0);
            acc[n] = __builtin_amdgcn_mfma_f32_16x16x32_bf16(a1, b0, acc[n], 0, 0, 0);
            acc[n] = __builtin_amdgcn_mfma_f32_16x16x32_bf16(a0, b1, acc[n], 0, 0, 0);
            acc[n] = __builtin_amdgcn_mfma_f32_16x16x32_bf16(a1, b1, acc[n], 0, 0, 0);
            acc[n] = __builtin_amdgcn_mfma_f32_16x16x32_bf16(a2, b0, acc[n], 0, 0, 0);
            acc[n] = __builtin_amdgcn_mfma_f32_16x16x32_bf16(a0, b2, acc[n], 0, 0, 0);
        }
    }
    int rbase = blockIdx.x * 64 + w * 16 + kq * 4;
#pragma unroll
    for (int reg = 0; reg < 4; ++reg) {
        int r = rbase + reg;
        if (r < Nn) {
            float s = dinv[r];
#pragma unroll
            for (int n = 0; n < 8; ++n)
                hw[(size_t)r * Hd + n * 16 + m] = acc[n][reg] * s;
        }
    }
}

// ---------------- aggregation: h[i] = relu(dinv[i]*(hw[i] + sum_src hw[src]) + b) ----
__global__ __launch_bounds__(256) void agg_kernel(const float* __restrict__ hw,
                            const int* __restrict__ row_ptr, const int* __restrict__ csr_src,
                            const float* __restrict__ dinv, const float* __restrict__ bias,
                            float* __restrict__ hout) {
    int node = blockIdx.x * 4 + (threadIdx.x >> 6);
    if (node >= Nn) return;
    int lane = threadIdx.x & 63;
    const v2f* hw2 = (const v2f*)hw;
    v2f a0 = hw2[(size_t)node * 64 + lane];   // self loop (hw pre-scaled by dinv[src])
    v2f a1 = 0.f, a2 = 0.f, a3 = 0.f;
    int e0 = row_ptr[node], e1 = row_ptr[node + 1];
    int e = e0;
    for (; e + 3 < e1; e += 4) {
        int s0 = __builtin_nontemporal_load(csr_src + e);
        int s1 = __builtin_nontemporal_load(csr_src + e + 1);
        int s2 = __builtin_nontemporal_load(csr_src + e + 2);
        int s3 = __builtin_nontemporal_load(csr_src + e + 3);
        a0 += hw2[(size_t)s0 * 64 + lane];
        a1 += hw2[(size_t)s1 * 64 + lane];
        a2 += hw2[(size_t)s2 * 64 + lane];
        a3 += hw2[(size_t)s3 * 64 + lane];
    }
    for (; e < e1; ++e) {
        int s0 = __builtin_nontemporal_load(csr_src + e);
        a0 += hw2[(size_t)s0 * 64 + lane];
    }
    v2f acc = (a0 + a1) + (a2 + a3);
    float d = dinv[node];
    v2f bv = ((const v2f*)bias)[lane];
    v2f o;
    o.x = fmaxf(fmaf(d, acc.x, bv.x), 0.f);
    o.y = fmaxf(fmaf(d, acc.y, bv.y), 0.f);
    ((v2f*)hout)[(size_t)node * 64 + lane] = o;
}

// ---------------- fused tail (1024 thr): topk -> conv -> lin1 -> lin2 ----------
__global__ __launch_bounds__(1024) void tail_kernel(const float* __restrict__ h,
                            const int* __restrict__ bstart,
                            const float* __restrict__ wT2, const float* __restrict__ conv_b,
                            const float* __restrict__ l1w, const float* __restrict__ l1b,
                            const float* __restrict__ l2w, const float* __restrict__ l2b,
                            float* __restrict__ out) {
    __shared__ float vals[CAP];          // 8 KB
    __shared__ float xcl[Kt][130];       // 15.6 KB, padded rows
    __shared__ float fl[CO * LOUT];      // 3.3 KB
    __shared__ float pz[8][Hd];          // 4 KB
    __shared__ float z[Hd];
    __shared__ float rv[16];
    __shared__ int ri[16];
    __shared__ int selS[Kt];
    int b = blockIdx.x, tid = threadIdx.x;

    // --- top-K select (descending last feature, tie: smaller idx) ---
    int s0 = bstart[b], s1 = bstart[b + 1];
    int n = s1 - s0;
    int nc = n < CAP ? n : CAP;
    for (int j = tid; j < nc; j += 1024)
        vals[j] = h[(size_t)(s0 + j) * Hd + (Hd - 1)];
    __syncthreads();
    for (int k = 0; k < Kt; ++k) {
        float bv = -1.f;
        int bi = 0x7fffffff;
        for (int j = tid; j < nc; j += 1024) {
            float v = vals[j];
            if (v > bv || (v == bv && j < bi)) { bv = v; bi = j; }
        }
        for (int off = 32; off > 0; off >>= 1) {
            float ov = __shfl_down(bv, off);
            int oi = __shfl_down(bi, off);
            if (ov > bv || (ov == bv && oi < bi)) { bv = ov; bi = oi; }
        }
        int wid = tid >> 6;
        if ((tid & 63) == 0) { rv[wid] = bv; ri[wid] = bi; }
        __syncthreads();
        if (tid == 0) {
            float fv = rv[0]; int fi = ri[0];
            for (int w = 1; w < 16; ++w) {
                if (rv[w] > fv || (rv[w] == fv && ri[w] < fi)) { fv = rv[w]; fi = ri[w]; }
            }
            if (k < n) {
                selS[k] = s0 + fi;
                vals[fi] = -1.f;   // relu output >= 0, so -1 can never win again
            } else {
                selS[k] = -1;
            }
        }
        __syncthreads();
    }
    // --- gather pooled tile straight into LDS ---
    for (int i = tid; i < Kt * Hd; i += 1024) {
        int t = i >> 7, c = i & 127;
        int s = selS[t];
        xcl[t][c] = (s >= 0) ? h[(size_t)s * Hd + c] : 0.f;
    }
    __syncthreads();
    // --- conv: fl[o*26+t] = relu(conv_b[o] + xc . w), one output per thread ---
    if (tid < CO * LOUT) {
        int o = tid / LOUT, t = tid - o * LOUT;
        float acc = conv_b[o];
#pragma unroll
        for (int k = 0; k < KW; ++k) {
            const float* xr = &xcl[t + k][0];
            const float* wr = wT2 + ((size_t)o * KW + k) * Hd;
#pragma unroll 8
            for (int c4 = 0; c4 < 32; ++c4) {
                float2 xa = *(const float2*)(xr + c4 * 4);
                float2 xb = *(const float2*)(xr + c4 * 4 + 2);
                float4 wv = *(const float4*)(wr + c4 * 4);
                acc = fmaf(xa.x, wv.x, acc);
                acc = fmaf(xa.y, wv.y, acc);
                acc = fmaf(xb.x, wv.z, acc);
                acc = fmaf(xb.y, wv.w, acc);
            }
        }
        fl[tid] = fmaxf(acc, 0.f);
    }
    __syncthreads();
    // --- lin1: 8 m-chunks of 104, all 1024 threads active ---
    int hh = tid & 127, chunk = tid >> 7;
    int m0 = chunk * 104;
    float acc = 0.f;
    const float* lw = l1w + (size_t)m0 * Hd + hh;
#pragma unroll 8
    for (int m = 0; m < 104; ++m)
        acc = fmaf(fl[m0 + m], lw[(size_t)m * Hd], acc);
    pz[chunk][hh] = acc;
    __syncthreads();
    if (tid < Hd) {
        float a = l1b[tid];
#pragma unroll
        for (int q = 0; q < 8; ++q) a += pz[q][tid];
        z[tid] = fmaxf(a, 0.f);
    }
    __syncthreads();
    if (tid < 10) {
        float a2 = l2b[tid];
        for (int j = 0; j < Hd; ++j)
            a2 = fmaf(z[j], l2w[j * 10 + tid], a2);
        out[b * 10 + tid] = a2;
    }
}

extern "C" void kernel_launch(void* const* d_in, const int* in_sizes, int n_in,
                              void* d_out, int out_size, void* d_ws, size_t ws_size,
                              hipStream_t stream) {
    const float* x      = (const float*)d_in[0];
    const int*   ei     = (const int*)d_in[1];
    const int*   batch  = (const int*)d_in[2];
    const float* W0     = (const float*)d_in[3];
    const float* b0     = (const float*)d_in[4];
    const float* W1     = (const float*)d_in[5];
    const float* b1     = (const float*)d_in[6];
    const float* W2     = (const float*)d_in[7];
    const float* b2     = (const float*)d_in[8];
    const float* conv_w = (const float*)d_in[9];
    const float* conv_b = (const float*)d_in[10];
    const float* l1w    = (const float*)d_in[11];
    const float* l1b    = (const float*)d_in[12];
    const float* l2w    = (const float*)d_in[13];
    const float* l2b    = (const float*)d_in[14];
    float* out = (float*)d_out;

    // workspace layout
    int* wsI = (int*)d_ws;
    size_t off = 0;
    int*   deg_i   = wsI + off; off += Nn;
    int*   cnt     = wsI + off; off += Nn;
    int*   row_ptr = wsI + off; off += 50004;
    int*   bstart  = wsI + off; off += 132;
    float* dinv    = (float*)(wsI + off); off += Nn;
    int*   bsum    = wsI + off; off += 256;
    int*   csr_src = wsI + off; off += Ee;
    off = (off + 3) & ~(size_t)3;        // 16B align
    ushort* Bph  = (ushort*)(wsI + off); off += 3 * 16384 / 2;   // packed W split hi
    ushort* Bpm  = (ushort*)(wsI + off); off += 3 * 16384 / 2;   // packed W split mid
    ushort* Bpl  = (ushort*)(wsI + off); off += 3 * 16384 / 2;   // packed W split lo
    float* hw    = (float*)(wsI + off); off += (size_t)Nn * Hd;
    float* hbuf  = (float*)(wsI + off); off += (size_t)Nn * Hd;
    float* wT2   = (float*)(wsI + off); off += CO * KW * Hd;

    // 1. init + W prep (one dispatch)
    initwprep_kernel<<<(Nn + 255) / 256, 256, 0, stream>>>(deg_i, cnt, bstart,
        conv_w, wT2, W0, W1, W2, Bph, Bpm, Bpl);
    // 2. degree histogram + batch starts
    count_kernel<<<(Ee + 255) / 256, 256, 0, stream>>>(ei, batch, deg_i, bstart);
    // 3. scan: block sums, then merged (redundant-scan + local scan)
    scanA_kernel<<<SCB, 256, 0, stream>>>(deg_i, dinv, bsum);
    scanBC_kernel<<<SCB, 256, 0, stream>>>(deg_i, bsum, row_ptr, bstart);
    // 4. CSR fill
    fill_kernel<<<(Ee + 255) / 256, 256, 0, stream>>>(ei, row_ptr, cnt, csr_src);

    // 5. three GCN layers (MFMA matmul + gather-aggregate)
    dim3 mmGrid((Nn + 63) / 64);
    dim3 aggGrid((Nn + 3) / 4);
    mmx_kernel<<<mmGrid, 256, 0, stream>>>(x, Bph, Bpm, Bpl, dinv, hw);
    agg_kernel<<<aggGrid, 256, 0, stream>>>(hw, row_ptr, csr_src, dinv, b0, hbuf);
    mmx_kernel<<<mmGrid, 256, 0, stream>>>(hbuf, Bph + 16384, Bpm + 16384, Bpl + 16384, dinv, hw);
    agg_kernel<<<aggGrid, 256, 0, stream>>>(hw, row_ptr, csr_src, dinv, b1, hbuf);
    mmx_kernel<<<mmGrid, 256, 0, stream>>>(hbuf, Bph + 32768, Bpm + 32768, Bpl + 32768, dinv, hw);
    agg_kernel<<<aggGrid, 256, 0, stream>>>(hw, row_ptr, csr_src, dinv, b2, hbuf);

    // 6. fused tail: topk + conv + lin1 + lin2 (one dispatch, 1024 threads)
    tail_kernel<<<Bg, 1024, 0, stream>>>(hbuf, bstart, wT2, conv_b,
                                         l1w, l1b, l2w, l2b, out);
}

// Round 13
// 449.953 us; speedup vs baseline: 1.1014x; 1.1014x over previous
//
#include <hip/hip_runtime.h>
#include <math.h>

#define Nn 50000
#define Ee 600000
#define Bg 128      // batches (graphs)
#define Hd 128      // hidden dim
#define Kt 30       // sortpool K
#define CO 32       // conv out channels
#define KW 5        // conv kernel
#define LOUT 26     // K - KW + 1
#define CAP 2048    // per-batch node cap for topk LDS (max real count ~460)
#define SCB 196     // ceil(50000/256) scan blocks

typedef float v2f __attribute__((ext_vector_type(2)));
typedef short bf16x8 __attribute__((ext_vector_type(8)));
typedef float f32x4 __attribute__((ext_vector_type(4)));

// bf16 round-to-nearest-even helpers (branchless, finite inputs)
__device__ __forceinline__ unsigned short bfr(float v) {
    unsigned u = __builtin_bit_cast(unsigned, v);
    unsigned r = (u + 0x7FFFu + ((u >> 16) & 1u)) >> 16;
    return (unsigned short)r;
}
__device__ __forceinline__ float bff(unsigned short h) {
    unsigned u = ((unsigned)h) << 16;
    return __builtin_bit_cast(float, u);
}

// ---------------- init + conv_w transpose + W 3-way split/pack ----------------
__global__ void initwprep_kernel(int* __restrict__ deg_i, int* __restrict__ cnt,
                            int* __restrict__ bstart,
                            const float* __restrict__ conv_w, float* __restrict__ wT2,
                            const float* __restrict__ W0, const float* __restrict__ W1,
                            const float* __restrict__ W2,
                            ushort* __restrict__ Bph, ushort* __restrict__ Bpm,
                            ushort* __restrict__ Bpl) {
    int i = blockIdx.x * 256 + threadIdx.x;
    if (i < Nn) { deg_i[i] = 1; cnt[i] = 0; }   // deg starts at 1 (self loop)
    if (i <= Bg) bstart[i] = Nn;                // sentinel
    if (i < CO * KW * Hd) {                     // wT2[o][k][ci] = conv_w[o][ci][k]
        int ci = i & 127;
        int r = i >> 7;          // o*KW + k
        int o = r / KW, k = r - o * KW;
        wT2[i] = conv_w[((size_t)o * Hd + ci) * KW + k];
    }
    if (i < 3 * 2048) {                          // W split+pack, B-fragment layout
        int l = i >> 11;
        int r = i & 2047;
        int kc = r >> 9;
        int n = (r >> 6) & 7;
        int lane = r & 63;
        int m = lane & 15, kq = lane >> 4;
        const float* W = (l == 0) ? W0 : (l == 1) ? W1 : W2;
        int col = n * 16 + m;
        size_t off = ((size_t)l * 2048 + (size_t)((kc * 8 + n) * 64 + lane)) * 8;
#pragma unroll
        for (int j = 0; j < 8; ++j) {
            float v = W[(size_t)(kc * 32 + kq * 8 + j) * Hd + col];
            unsigned short h = bfr(v);
            float r1 = v - bff(h);
            unsigned short mid = bfr(r1);
            Bph[off + j] = h;
            Bpm[off + j] = mid;
            Bpl[off + j] = bfr(r1 - bff(mid));
        }
    }
}

// ---------------- degree histogram + batch starts (boundary detect) ----------
__global__ void count_kernel(const int* __restrict__ ei, const int* __restrict__ batch,
                             int* __restrict__ deg_i, int* __restrict__ bstart) {
    int i = blockIdx.x * 256 + threadIdx.x;
    if (i < Ee) atomicAdd(&deg_i[ei[Ee + i]], 1);       // col = edge_index[1]
    if (i < Nn) {
        int b = batch[i];
        if (i == 0) {
            bstart[b] = 0;
        } else {
            int bp = batch[i - 1];
            if (bp != b) bstart[b] = i;
        }
    }
}

// ---------------- scan phase A: block sums of (deg-1), dinv ----------------
__global__ __launch_bounds__(256) void scanA_kernel(const int* __restrict__ deg_i,
                            float* __restrict__ dinv, int* __restrict__ bsum) {
    __shared__ int s[256];
    int tid = threadIdx.x;
    int i = blockIdx.x * 256 + tid;
    int v = 0;
    if (i < Nn) {
        int d = deg_i[i];
        dinv[i] = 1.0f / sqrtf((float)d);
        v = d - 1;
    }
    s[tid] = v;
    __syncthreads();
    for (int off = 128; off > 0; off >>= 1) {
        if (tid < off) s[tid] += s[tid + off];
        __syncthreads();
    }
    if (tid == 0) bsum[blockIdx.x] = s[0];
}

// ---------------- scan phase BC: redundant block-sum scan + local scan ------
__global__ __launch_bounds__(256) void scanBC_kernel(const int* __restrict__ deg_i,
                            const int* __restrict__ bsum, int* __restrict__ row_ptr,
                            int* __restrict__ bstart) {
    __shared__ int ls[256];
    __shared__ int boffS;
    int tid = threadIdx.x;
    int v = (tid < SCB) ? bsum[tid] : 0;
    ls[tid] = v;
    __syncthreads();
    for (int off = 1; off < 256; off <<= 1) {
        int t = (tid >= off) ? ls[tid - off] : 0;
        __syncthreads();
        ls[tid] += t;
        __syncthreads();
    }
    if (tid == 0) boffS = (blockIdx.x > 0) ? ls[blockIdx.x - 1] : 0;
    __syncthreads();
    int boff = boffS;
    int i = blockIdx.x * 256 + tid;
    int v2 = (i < Nn) ? deg_i[i] - 1 : 0;
    ls[tid] = v2;
    __syncthreads();
    for (int off = 1; off < 256; off <<= 1) {
        int t = (tid >= off) ? ls[tid - off] : 0;
        __syncthreads();
        ls[tid] += t;
        __syncthreads();
    }
    if (i < Nn) row_ptr[i + 1] = ls[tid] + boff;
    if (i == 0) row_ptr[0] = 0;
    if (blockIdx.x == 0 && tid == 0) {   // empty batches inherit next start
        for (int b = Bg - 1; b >= 0; --b)
            if (bstart[b] == Nn) bstart[b] = bstart[b + 1];
    }
}

// ---------------- CSR fill (edges grouped by destination col) ----------------
__global__ void fill_kernel(const int* __restrict__ ei, const int* __restrict__ row_ptr,
                            int* __restrict__ cnt, int* __restrict__ csr_src) {
    int e = blockIdx.x * 256 + threadIdx.x;
    if (e >= Ee) return;
    int c = ei[Ee + e];
    int r = ei[e];
    int p = row_ptr[c] + atomicAdd(&cnt[c], 1);
    csr_src[p] = r;
}

// ---------------- MFMA matmul: hw[i] = dinv[i] * (Hin[i] @ W) ----------------
// 3-way split-bf16 (near-fp32). Retained products: a0b0,a1b0,a0b1,a1b1,a2b0,a0b2.
__global__ __launch_bounds__(256) void mmx_kernel(const float* __restrict__ Hin,
                            const ushort* __restrict__ Bph, const ushort* __restrict__ Bpm,
                            const ushort* __restrict__ Bpl,
                            const float* __restrict__ dinv, float* __restrict__ hw) {
    int tid = threadIdx.x;
    int w = tid >> 6, lane = tid & 63;
    int m = lane & 15, kq = lane >> 4;
    int rowA = blockIdx.x * 64 + w * 16 + m;
    bool va = rowA < Nn;
    const float* ap = Hin + (size_t)rowA * Hd;
    f32x4 acc[8];
#pragma unroll
    for (int n = 0; n < 8; ++n) acc[n] = (f32x4)0.f;
#pragma unroll
    for (int kc = 0; kc < 4; ++kc) {
        bf16x8 a0 = (bf16x8)0, a1 = (bf16x8)0, a2 = (bf16x8)0;
        if (va) {
            float av[8];
            *(float4*)&av[0] = *(const float4*)(ap + kc * 32 + kq * 8);
            *(float4*)&av[4] = *(const float4*)(ap + kc * 32 + kq * 8 + 4);
#pragma unroll
            for (int j = 0; j < 8; ++j) {
                unsigned short h = bfr(av[j]);
                float r1 = av[j] - bff(h);
                unsigned short mid = bfr(r1);
                a0[j] = (short)h;
                a1[j] = (short)mid;
                a2[j] = (short)bfr(r1 - bff(mid));
            }
        }
        const ushort* bhp = Bph + (size_t)((kc * 8) * 64 + lane) * 8;
        const ushort* bmp = Bpm + (size_t)((kc * 8) * 64 + lane) * 8;
        const ushort* blp = Bpl + (size_t)((kc * 8) * 64 + lane) * 8;
#pragma unroll
        for (int n = 0; n < 8; ++n) {
            bf16x8 b0 = *(const bf16x8*)(bhp + (size_t)n * 64 * 8);
            bf16x8 b1 = *(const bf16x8*)(bmp + (size_t)n * 64 * 8);
            bf16x8 b2 = *(const bf16x8*)(blp + (size_t)n * 64 * 8);
            acc[n] = __builtin_amdgcn_mfma_f32_16x16x32_bf16(a0, b0, acc[n], 0, 0, 0);
            acc[n] = __builtin_amdgcn_mfma_f32_16x16x32_bf16(a1, b0, acc[n], 0, 0, 0);
            acc[n] = __builtin_amdgcn_mfma_f32_16x16x32_bf16(a0, b1, acc[n], 0, 0, 0);
            acc[n] = __builtin_amdgcn_mfma_f32_16x16x32_bf16(a1, b1, acc[n], 0, 0, 0);
            acc[n] = __builtin_amdgcn_mfma_f32_16x16x32_bf16(a2, b0, acc[n], 0, 0, 0);
            acc[n] = __builtin_amdgcn_mfma_f32_16x16x32_bf16(a0, b2, acc[n], 0, 0, 0);
        }
    }
    int rbase = blockIdx.x * 64 + w * 16 + kq * 4;
#pragma unroll
    for (int reg = 0; reg < 4; ++reg) {
        int r = rbase + reg;
        if (r < Nn) {
            float s = dinv[r];
#pragma unroll
            for (int n = 0; n < 8; ++n)
                hw[(size_t)r * Hd + n * 16 + m] = acc[n][reg] * s;
        }
    }
}

// ---------------- aggregation: h[i] = relu(dinv[i]*(hw[i] + sum_src hw[src]) + b) ----
__global__ __launch_bounds__(256) void agg_kernel(const float* __restrict__ hw,
                            const int* __restrict__ row_ptr, const int* __restrict__ csr_src,
                            const float* __restrict__ dinv, const float* __restrict__ bias,
                            float* __restrict__ hout) {
    int node = blockIdx.x * 4 + (threadIdx.x >> 6);
    if (node >= Nn) return;
    int lane = threadIdx.x & 63;
    const v2f* hw2 = (const v2f*)hw;
    v2f a0 = hw2[(size_t)node * 64 + lane];   // self loop (hw pre-scaled by dinv[src])
    v2f a1 = 0.f, a2 = 0.f, a3 = 0.f;
    int e0 = row_ptr[node], e1 = row_ptr[node + 1];
    int e = e0;
    for (; e + 3 < e1; e += 4) {
        int s0 = __builtin_nontemporal_load(csr_src + e);
        int s1 = __builtin_nontemporal_load(csr_src + e + 1);
        int s2 = __builtin_nontemporal_load(csr_src + e + 2);
        int s3 = __builtin_nontemporal_load(csr_src + e + 3);
        a0 += hw2[(size_t)s0 * 64 + lane];
        a1 += hw2[(size_t)s1 * 64 + lane];
        a2 += hw2[(size_t)s2 * 64 + lane];
        a3 += hw2[(size_t)s3 * 64 + lane];
    }
    for (; e < e1; ++e) {
        int s0 = __builtin_nontemporal_load(csr_src + e);
        a0 += hw2[(size_t)s0 * 64 + lane];
    }
    v2f acc = (a0 + a1) + (a2 + a3);
    float d = dinv[node];
    v2f bv = ((const v2f*)bias)[lane];
    v2f o;
    o.x = fmaxf(fmaf(d, acc.x, bv.x), 0.f);
    o.y = fmaxf(fmaf(d, acc.y, bv.y), 0.f);
    ((v2f*)hout)[(size_t)node * 64 + lane] = o;
}

// ---------------- fused tail (1024 thr): rank-select topk -> conv -> lin1 -> lin2 ----
// topk via single-pass rank: rank_j = #{i: v_i>v_j or (v_i==v_j and i<j)};
// rank<Kt => selS[rank]=j. Inner loop index is wave-uniform -> LDS broadcast.
__global__ __launch_bounds__(1024) void tail_kernel(const float* __restrict__ h,
                            const int* __restrict__ bstart,
                            const float* __restrict__ wT2, const float* __restrict__ conv_b,
                            const float* __restrict__ l1w, const float* __restrict__ l1b,
                            const float* __restrict__ l2w, const float* __restrict__ l2b,
                            float* __restrict__ out) {
    __shared__ float vals[CAP];          // 8 KB
    __shared__ float xcl[Kt][130];       // 15.6 KB, padded rows
    __shared__ float fl[CO * LOUT];      // 3.3 KB
    __shared__ float pz[8][Hd];          // 4 KB
    __shared__ float z[Hd];
    __shared__ int selS[Kt];
    int b = blockIdx.x, tid = threadIdx.x;

    // --- load last-feature column; init selS ---
    int s0 = bstart[b], s1 = bstart[b + 1];
    int n = s1 - s0;
    int nc = n < CAP ? n : CAP;
    if (tid < Kt) selS[tid] = -1;
    for (int j = tid; j < nc; j += 1024)
        vals[j] = h[(size_t)(s0 + j) * Hd + (Hd - 1)];
    __syncthreads();

    // --- rank pass (descending value, tie: smaller index) ---
    for (int j = tid; j < nc; j += 1024) {
        float vj = vals[j];
        int rank = 0;
        for (int i = 0; i < nc; ++i) {          // i wave-uniform -> broadcast read
            float vi = vals[i];
            rank += (vi > vj || (vi == vj && i < j)) ? 1 : 0;
        }
        if (rank < Kt) selS[rank] = s0 + j;
    }
    __syncthreads();

    // --- gather pooled tile straight into LDS ---
    for (int i = tid; i < Kt * Hd; i += 1024) {
        int t = i >> 7, c = i & 127;
        int s = selS[t];
        xcl[t][c] = (s >= 0) ? h[(size_t)s * Hd + c] : 0.f;
    }
    __syncthreads();
    // --- conv: fl[o*26+t] = relu(conv_b[o] + xc . w), one output per thread ---
    if (tid < CO * LOUT) {
        int o = tid / LOUT, t = tid - o * LOUT;
        float acc = conv_b[o];
#pragma unroll
        for (int k = 0; k < KW; ++k) {
            const float* xr = &xcl[t + k][0];
            const float* wr = wT2 + ((size_t)o * KW + k) * Hd;
#pragma unroll 8
            for (int c4 = 0; c4 < 32; ++c4) {
                float2 xa = *(const float2*)(xr + c4 * 4);
                float2 xb = *(const float2*)(xr + c4 * 4 + 2);
                float4 wv = *(const float4*)(wr + c4 * 4);
                acc = fmaf(xa.x, wv.x, acc);
                acc = fmaf(xa.y, wv.y, acc);
                acc = fmaf(xb.x, wv.z, acc);
                acc = fmaf(xb.y, wv.w, acc);
            }
        }
        fl[tid] = fmaxf(acc, 0.f);
    }
    __syncthreads();
    // --- lin1: 8 m-chunks of 104, all 1024 threads active ---
    int hh = tid & 127, chunk = tid >> 7;
    int m0 = chunk * 104;
    float acc = 0.f;
    const float* lw = l1w + (size_t)m0 * Hd + hh;
#pragma unroll 8
    for (int m = 0; m < 104; ++m)
        acc = fmaf(fl[m0 + m], lw[(size_t)m * Hd], acc);
    pz[chunk][hh] = acc;
    __syncthreads();
    if (tid < Hd) {
        float a = l1b[tid];
#pragma unroll
        for (int q = 0; q < 8; ++q) a += pz[q][tid];
        z[tid] = fmaxf(a, 0.f);
    }
    __syncthreads();
    if (tid < 10) {
        float a2 = l2b[tid];
        for (int j = 0; j < Hd; ++j)
            a2 = fmaf(z[j], l2w[j * 10 + tid], a2);
        out[b * 10 + tid] = a2;
    }
}

extern "C" void kernel_launch(void* const* d_in, const int* in_sizes, int n_in,
                              void* d_out, int out_size, void* d_ws, size_t ws_size,
                              hipStream_t stream) {
    const float* x      = (const float*)d_in[0];
    const int*   ei     = (const int*)d_in[1];
    const int*   batch  = (const int*)d_in[2];
    const float* W0     = (const float*)d_in[3];
    const float* b0     = (const float*)d_in[4];
    const float* W1     = (const float*)d_in[5];
    const float* b1     = (const float*)d_in[6];
    const float* W2     = (const float*)d_in[7];
    const float* b2     = (const float*)d_in[8];
    const float* conv_w = (const float*)d_in[9];
    const float* conv_b = (const float*)d_in[10];
    const float* l1w    = (const float*)d_in[11];
    const float* l1b    = (const float*)d_in[12];
    const float* l2w    = (const float*)d_in[13];
    const float* l2b    = (const float*)d_in[14];
    float* out = (float*)d_out;

    // workspace layout
    int* wsI = (int*)d_ws;
    size_t off = 0;
    int*   deg_i   = wsI + off; off += Nn;
    int*   cnt     = wsI + off; off += Nn;
    int*   row_ptr = wsI + off; off += 50004;
    int*   bstart  = wsI + off; off += 132;
    float* dinv    = (float*)(wsI + off); off += Nn;
    int*   bsum    = wsI + off; off += 256;
    int*   csr_src = wsI + off; off += Ee;
    off = (off + 3) & ~(size_t)3;        // 16B align
    ushort* Bph  = (ushort*)(wsI + off); off += 3 * 16384 / 2;   // packed W split hi
    ushort* Bpm  = (ushort*)(wsI + off); off += 3 * 16384 / 2;   // packed W split mid
    ushort* Bpl  = (ushort*)(wsI + off); off += 3 * 16384 / 2;   // packed W split lo
    float* hw    = (float*)(wsI + off); off += (size_t)Nn * Hd;
    float* hbuf  = (float*)(wsI + off); off += (size_t)Nn * Hd;
    float* wT2   = (float*)(wsI + off); off += CO * KW * Hd;

    // 1. init + W prep (one dispatch)
    initwprep_kernel<<<(Nn + 255) / 256, 256, 0, stream>>>(deg_i, cnt, bstart,
        conv_w, wT2, W0, W1, W2, Bph, Bpm, Bpl);
    // 2. degree histogram + batch starts
    count_kernel<<<(Ee + 255) / 256, 256, 0, stream>>>(ei, batch, deg_i, bstart);
    // 3. scan: block sums, then merged (redundant-scan + local scan)
    scanA_kernel<<<SCB, 256, 0, stream>>>(deg_i, dinv, bsum);
    scanBC_kernel<<<SCB, 256, 0, stream>>>(deg_i, bsum, row_ptr, bstart);
    // 4. CSR fill
    fill_kernel<<<(Ee + 255) / 256, 256, 0, stream>>>(ei, row_ptr, cnt, csr_src);

    // 5. three GCN layers (MFMA matmul + gather-aggregate)
    dim3 mmGrid((Nn + 63) / 64);
    dim3 aggGrid((Nn + 3) / 4);
    mmx_kernel<<<mmGrid, 256, 0, stream>>>(x, Bph, Bpm, Bpl, dinv, hw);
    agg_kernel<<<aggGrid, 256, 0, stream>>>(hw, row_ptr, csr_src, dinv, b0, hbuf);
    mmx_kernel<<<mmGrid, 256, 0, stream>>>(hbuf, Bph + 16384, Bpm + 16384, Bpl + 16384, dinv, hw);
    agg_kernel<<<aggGrid, 256, 0, stream>>>(hw, row_ptr, csr_src, dinv, b1, hbuf);
    mmx_kernel<<<mmGrid, 256, 0, stream>>>(hbuf, Bph + 32768, Bpm + 32768, Bpl + 32768, dinv, hw);
    agg_kernel<<<aggGrid, 256, 0, stream>>>(hw, row_ptr, csr_src, dinv, b2, hbuf);

    // 6. fused tail: rank-topk + conv + lin1 + lin2 (one dispatch)
    tail_kernel<<<Bg, 1024, 0, stream>>>(hbuf, bstart, wT2, conv_b,
                                         l1w, l1b, l2w, l2b, out);
}

// Round 14
// 443.700 us; speedup vs baseline: 1.1170x; 1.0141x over previous
//
#include <hip/hip_runtime.h>
#include <math.h>

#define Nn 50000
#define Ee 600000
#define Bg 128      // batches (graphs)
#define Hd 128      // hidden dim
#define Kt 30       // sortpool K
#define CO 32       // conv out channels
#define KW 5        // conv kernel
#define LOUT 26     // K - KW + 1
#define CAP 2048    // per-batch node cap for topk LDS (max real count ~460)
#define SCB 196     // ceil(50000/256) scan blocks
#define MMB 782     // mmx blocks = ceil(50000/64)

typedef float v2f __attribute__((ext_vector_type(2)));
typedef short bf16x8 __attribute__((ext_vector_type(8)));
typedef float f32x4 __attribute__((ext_vector_type(4)));

// bf16 round-to-nearest-even helpers (branchless, finite inputs)
__device__ __forceinline__ unsigned short bfr(float v) {
    unsigned u = __builtin_bit_cast(unsigned, v);
    unsigned r = (u + 0x7FFFu + ((u >> 16) & 1u)) >> 16;
    return (unsigned short)r;
}
__device__ __forceinline__ float bff(unsigned short h) {
    unsigned u = ((unsigned)h) << 16;
    return __builtin_bit_cast(float, u);
}

// ---- count + batch starts + conv_w transpose + W 3-way split/pack ----------
// deg_i/cnt/bstart pre-set to -1 (0xFF memset). deg_i[c] ends at (#incoming - 1).
__global__ void countpack_kernel(const int* __restrict__ ei, const int* __restrict__ batch,
                            int* __restrict__ deg_i, int* __restrict__ bstart,
                            const float* __restrict__ conv_w, float* __restrict__ wT2,
                            const float* __restrict__ W0, const float* __restrict__ W1,
                            const float* __restrict__ W2,
                            ushort* __restrict__ Bph, ushort* __restrict__ Bpm,
                            ushort* __restrict__ Bpl) {
    int i = blockIdx.x * 256 + threadIdx.x;
    if (i < Ee) atomicAdd(&deg_i[ei[Ee + i]], 1);       // col = edge_index[1]
    if (i < Nn) {
        int b = batch[i];
        if (i == 0) bstart[b] = 0;
        else if (batch[i - 1] != b) bstart[b] = i;
    }
    if (i == 0) bstart[Bg] = Nn;
    if (i < CO * KW * Hd) {                     // wT2[o][k][ci] = conv_w[o][ci][k]
        int ci = i & 127;
        int r = i >> 7;          // o*KW + k
        int o = r / KW, k = r - o * KW;
        wT2[i] = conv_w[((size_t)o * Hd + ci) * KW + k];
    }
    if (i < 3 * 2048) {                          // W split+pack, B-fragment layout
        int l = i >> 11;
        int r = i & 2047;
        int kc = r >> 9;
        int n = (r >> 6) & 7;
        int lane = r & 63;
        int m = lane & 15, kq = lane >> 4;
        const float* W = (l == 0) ? W0 : (l == 1) ? W1 : W2;
        int col = n * 16 + m;
        size_t off = ((size_t)l * 2048 + (size_t)((kc * 8 + n) * 64 + lane)) * 8;
#pragma unroll
        for (int j = 0; j < 8; ++j) {
            float v = W[(size_t)(kc * 32 + kq * 8 + j) * Hd + col];
            unsigned short h = bfr(v);
            float r1 = v - bff(h);
            unsigned short mid = bfr(r1);
            Bph[off + j] = h;
            Bpm[off + j] = mid;
            Bpl[off + j] = bfr(r1 - bff(mid));
        }
    }
}

// ---- single scan dispatch: per-block direct offset sum + local scan + dinv --
// offset for block b = sum of row lengths (deg_i[j]+1) over j < b*256, computed
// by direct strided summation (L2-resident). Also: dinv, empty-batch fix.
__global__ __launch_bounds__(256) void scanBC2_kernel(const int* __restrict__ deg_i,
                            int* __restrict__ row_ptr, float* __restrict__ dinv,
                            int* __restrict__ bstart) {
    __shared__ int ls[256];
    __shared__ int boffS;
    int tid = threadIdx.x;
    int b = blockIdx.x;
    int s = 0;
    for (int k = 0; k < b; ++k)                 // j = k*256+tid < b*256 <= 49920 < Nn
        s += deg_i[k * 256 + tid] + 1;
    ls[tid] = s;
    __syncthreads();
    for (int off = 128; off > 0; off >>= 1) {
        if (tid < off) ls[tid] += ls[tid + off];
        __syncthreads();
    }
    if (tid == 0) boffS = ls[0];
    __syncthreads();
    int boff = boffS;
    int i = b * 256 + tid;
    int v2 = 0;
    if (i < Nn) {
        int raw = deg_i[i];
        v2 = raw + 1;                           // CSR row length (= #incoming)
        dinv[i] = 1.0f / sqrtf((float)(raw + 2));  // degree incl. self loop
    }
    ls[tid] = v2;
    __syncthreads();
    for (int off = 1; off < 256; off <<= 1) {
        int t = (tid >= off) ? ls[tid - off] : 0;
        __syncthreads();
        ls[tid] += t;
        __syncthreads();
    }
    if (i < Nn) row_ptr[i + 1] = ls[tid] + boff;
    if (i == 0) row_ptr[0] = 0;
    if (b == 0 && tid == 0) {   // empty batches inherit next start (batch sorted)
        for (int bb = Bg - 1; bb >= 0; --bb)
            if (bstart[bb] == -1) bstart[bb] = bstart[bb + 1];
    }
}

// ---------------- MFMA matmul body (shared by mmx and mmxfill) ----------------
// 3-way split-bf16 (near-fp32). Retained products: a0b0,a1b0,a0b1,a1b1,a2b0,a0b2.
__device__ __forceinline__ void mmx_body(int bid, int tid,
                            const float* __restrict__ Hin,
                            const ushort* __restrict__ Bph, const ushort* __restrict__ Bpm,
                            const ushort* __restrict__ Bpl,
                            const float* __restrict__ dinv, float* __restrict__ hw) {
    int w = tid >> 6, lane = tid & 63;
    int m = lane & 15, kq = lane >> 4;
    int rowA = bid * 64 + w * 16 + m;
    bool va = rowA < Nn;
    const float* ap = Hin + (size_t)rowA * Hd;
    f32x4 acc[8];
#pragma unroll
    for (int n = 0; n < 8; ++n) acc[n] = (f32x4)0.f;
#pragma unroll
    for (int kc = 0; kc < 4; ++kc) {
        bf16x8 a0 = (bf16x8)0, a1 = (bf16x8)0, a2 = (bf16x8)0;
        if (va) {
            float av[8];
            *(float4*)&av[0] = *(const float4*)(ap + kc * 32 + kq * 8);
            *(float4*)&av[4] = *(const float4*)(ap + kc * 32 + kq * 8 + 4);
#pragma unroll
            for (int j = 0; j < 8; ++j) {
                unsigned short h = bfr(av[j]);
                float r1 = av[j] - bff(h);
                unsigned short mid = bfr(r1);
                a0[j] = (short)h;
                a1[j] = (short)mid;
                a2[j] = (short)bfr(r1 - bff(mid));
            }
        }
        const ushort* bhp = Bph + (size_t)((kc * 8) * 64 + lane) * 8;
        const ushort* bmp = Bpm + (size_t)((kc * 8) * 64 + lane) * 8;
        const ushort* blp = Bpl + (size_t)((kc * 8) * 64 + lane) * 8;
#pragma unroll
        for (int n = 0; n < 8; ++n) {
            bf16x8 b0 = *(const bf16x8*)(bhp + (size_t)n * 64 * 8);
            bf16x8 b1 = *(const bf16x8*)(bmp + (size_t)n * 64 * 8);
            bf16x8 b2 = *(const bf16x8*)(blp + (size_t)n * 64 * 8);
            acc[n] = __builtin_amdgcn_mfma_f32_16x16x32_bf16(a0, b0, acc[n], 0, 0, 0);
            acc[n] = __builtin_amdgcn_mfma_f32_16x16x32_bf16(a1, b0, acc[n], 0, 0, 0);
            acc[n] = __builtin_amdgcn_mfma_f32_16x16x32_bf16(a0, b1, acc[n], 0, 0, 0);
            acc[n] = __builtin_amdgcn_mfma_f32_16x16x32_bf16(a1, b1, acc[n], 0, 0, 0);
            acc[n] = __builtin_amdgcn_mfma_f32_16x16x32_bf16(a2, b0, acc[n], 0, 0, 0);
            acc[n] = __builtin_amdgcn_mfma_f32_16x16x32_bf16(a0, b2, acc[n], 0, 0, 0);
        }
    }
    int rbase = bid * 64 + w * 16 + kq * 4;
#pragma unroll
    for (int reg = 0; reg < 4; ++reg) {
        int r = rbase + reg;
        if (r < Nn) {
            float s = dinv[r];
#pragma unroll
            for (int n = 0; n < 8; ++n)
                hw[(size_t)r * Hd + n * 16 + m] = acc[n][reg] * s;
        }
    }
}

__global__ __launch_bounds__(256) void mmx_kernel(const float* __restrict__ Hin,
                            const ushort* __restrict__ Bph, const ushort* __restrict__ Bpm,
                            const ushort* __restrict__ Bpl,
                            const float* __restrict__ dinv, float* __restrict__ hw) {
    mmx_body(blockIdx.x, threadIdx.x, Hin, Bph, Bpm, Bpl, dinv, hw);
}

// ---- merged layer-0 matmul + CSR fill (independent work, block-range split) --
__global__ __launch_bounds__(256) void mmxfill_kernel(const float* __restrict__ Hin,
                            const ushort* __restrict__ Bph, const ushort* __restrict__ Bpm,
                            const ushort* __restrict__ Bpl,
                            const float* __restrict__ dinv, float* __restrict__ hw,
                            const int* __restrict__ ei, const int* __restrict__ row_ptr,
                            int* __restrict__ cnt, int* __restrict__ csr_src) {
    if (blockIdx.x < MMB) {
        mmx_body(blockIdx.x, threadIdx.x, Hin, Bph, Bpm, Bpl, dinv, hw);
    } else {
        int e = (blockIdx.x - MMB) * 256 + threadIdx.x;
        if (e < Ee) {
            int c = ei[Ee + e];
            int r = ei[e];
            int p = row_ptr[c] + atomicAdd(&cnt[c], 1) + 1;   // cnt starts at -1
            csr_src[p] = r;
        }
    }
}

// ---------------- aggregation: h[i] = relu(dinv[i]*(hw[i] + sum_src hw[src]) + b) ----
__global__ __launch_bounds__(256) void agg_kernel(const float* __restrict__ hw,
                            const int* __restrict__ row_ptr, const int* __restrict__ csr_src,
                            const float* __restrict__ dinv, const float* __restrict__ bias,
                            float* __restrict__ hout) {
    int node = blockIdx.x * 4 + (threadIdx.x >> 6);
    if (node >= Nn) return;
    int lane = threadIdx.x & 63;
    const v2f* hw2 = (const v2f*)hw;
    v2f a0 = hw2[(size_t)node * 64 + lane];   // self loop (hw pre-scaled by dinv[src])
    v2f a1 = 0.f, a2 = 0.f, a3 = 0.f;
    int e0 = row_ptr[node], e1 = row_ptr[node + 1];
    int e = e0;
    for (; e + 3 < e1; e += 4) {
        int s0 = __builtin_nontemporal_load(csr_src + e);
        int s1 = __builtin_nontemporal_load(csr_src + e + 1);
        int s2 = __builtin_nontemporal_load(csr_src + e + 2);
        int s3 = __builtin_nontemporal_load(csr_src + e + 3);
        a0 += hw2[(size_t)s0 * 64 + lane];
        a1 += hw2[(size_t)s1 * 64 + lane];
        a2 += hw2[(size_t)s2 * 64 + lane];
        a3 += hw2[(size_t)s3 * 64 + lane];
    }
    for (; e < e1; ++e) {
        int s0 = __builtin_nontemporal_load(csr_src + e);
        a0 += hw2[(size_t)s0 * 64 + lane];
    }
    v2f acc = (a0 + a1) + (a2 + a3);
    float d = dinv[node];
    v2f bv = ((const v2f*)bias)[lane];
    v2f o;
    o.x = fmaxf(fmaf(d, acc.x, bv.x), 0.f);
    o.y = fmaxf(fmaf(d, acc.y, bv.y), 0.f);
    ((v2f*)hout)[(size_t)node * 64 + lane] = o;
}

// ---------------- fused tail (1024 thr): rank-select topk -> conv -> lin1 -> lin2 ----
__global__ __launch_bounds__(1024) void tail_kernel(const float* __restrict__ h,
                            const int* __restrict__ bstart,
                            const float* __restrict__ wT2, const float* __restrict__ conv_b,
                            const float* __restrict__ l1w, const float* __restrict__ l1b,
                            const float* __restrict__ l2w, const float* __restrict__ l2b,
                            float* __restrict__ out) {
    __shared__ float vals[CAP];          // 8 KB
    __shared__ float xcl[Kt][130];       // 15.6 KB, padded rows
    __shared__ float fl[CO * LOUT];      // 3.3 KB
    __shared__ float pz[8][Hd];          // 4 KB
    __shared__ float z[Hd];
    __shared__ int selS[Kt];
    int b = blockIdx.x, tid = threadIdx.x;

    int s0 = bstart[b], s1 = bstart[b + 1];
    int n = s1 - s0;
    int nc = n < CAP ? n : CAP;
    if (tid < Kt) selS[tid] = -1;
    for (int j = tid; j < nc; j += 1024)
        vals[j] = h[(size_t)(s0 + j) * Hd + (Hd - 1)];
    __syncthreads();

    // rank pass (descending value, tie: smaller index)
    for (int j = tid; j < nc; j += 1024) {
        float vj = vals[j];
        int rank = 0;
        for (int i = 0; i < nc; ++i) {          // i wave-uniform -> LDS broadcast
            float vi = vals[i];
            rank += (vi > vj || (vi == vj && i < j)) ? 1 : 0;
        }
        if (rank < Kt) selS[rank] = s0 + j;
    }
    __syncthreads();

    for (int i = tid; i < Kt * Hd; i += 1024) {
        int t = i >> 7, c = i & 127;
        int s = selS[t];
        xcl[t][c] = (s >= 0) ? h[(size_t)s * Hd + c] : 0.f;
    }
    __syncthreads();
    if (tid < CO * LOUT) {
        int o = tid / LOUT, t = tid - o * LOUT;
        float acc = conv_b[o];
#pragma unroll
        for (int k = 0; k < KW; ++k) {
            const float* xr = &xcl[t + k][0];
            const float* wr = wT2 + ((size_t)o * KW + k) * Hd;
#pragma unroll 8
            for (int c4 = 0; c4 < 32; ++c4) {
                float2 xa = *(const float2*)(xr + c4 * 4);
                float2 xb = *(const float2*)(xr + c4 * 4 + 2);
                float4 wv = *(const float4*)(wr + c4 * 4);
                acc = fmaf(xa.x, wv.x, acc);
                acc = fmaf(xa.y, wv.y, acc);
                acc = fmaf(xb.x, wv.z, acc);
                acc = fmaf(xb.y, wv.w, acc);
            }
        }
        fl[tid] = fmaxf(acc, 0.f);
    }
    __syncthreads();
    int hh = tid & 127, chunk = tid >> 7;
    int m0 = chunk * 104;
    float acc = 0.f;
    const float* lw = l1w + (size_t)m0 * Hd + hh;
#pragma unroll 8
    for (int m = 0; m < 104; ++m)
        acc = fmaf(fl[m0 + m], lw[(size_t)m * Hd], acc);
    pz[chunk][hh] = acc;
    __syncthreads();
    if (tid < Hd) {
        float a = l1b[tid];
#pragma unroll
        for (int q = 0; q < 8; ++q) a += pz[q][tid];
        z[tid] = fmaxf(a, 0.f);
    }
    __syncthreads();
    if (tid < 10) {
        float a2 = l2b[tid];
        for (int j = 0; j < Hd; ++j)
            a2 = fmaf(z[j], l2w[j * 10 + tid], a2);
        out[b * 10 + tid] = a2;
    }
}

extern "C" void kernel_launch(void* const* d_in, const int* in_sizes, int n_in,
                              void* d_out, int out_size, void* d_ws, size_t ws_size,
                              hipStream_t stream) {
    const float* x      = (const float*)d_in[0];
    const int*   ei     = (const int*)d_in[1];
    const int*   batch  = (const int*)d_in[2];
    const float* W0     = (const float*)d_in[3];
    const float* b0     = (const float*)d_in[4];
    const float* W1     = (const float*)d_in[5];
    const float* b1     = (const float*)d_in[6];
    const float* W2     = (const float*)d_in[7];
    const float* b2     = (const float*)d_in[8];
    const float* conv_w = (const float*)d_in[9];
    const float* conv_b = (const float*)d_in[10];
    const float* l1w    = (const float*)d_in[11];
    const float* l1b    = (const float*)d_in[12];
    const float* l2w    = (const float*)d_in[13];
    const float* l2b    = (const float*)d_in[14];
    float* out = (float*)d_out;

    // workspace layout — deg_i, cnt, bstart contiguous for one 0xFF memset
    int* wsI = (int*)d_ws;
    size_t off = 0;
    int*   deg_i   = wsI + off; off += Nn;
    int*   cnt     = wsI + off; off += Nn;
    int*   bstart  = wsI + off; off += 132;
    int*   row_ptr = wsI + off; off += 50004;
    float* dinv    = (float*)(wsI + off); off += Nn;
    int*   csr_src = wsI + off; off += Ee;
    off = (off + 3) & ~(size_t)3;        // 16B align
    ushort* Bph  = (ushort*)(wsI + off); off += 3 * 16384 / 2;   // packed W split hi
    ushort* Bpm  = (ushort*)(wsI + off); off += 3 * 16384 / 2;   // packed W split mid
    ushort* Bpl  = (ushort*)(wsI + off); off += 3 * 16384 / 2;   // packed W split lo
    float* hw    = (float*)(wsI + off); off += (size_t)Nn * Hd;
    float* hbuf  = (float*)(wsI + off); off += (size_t)Nn * Hd;
    float* wT2   = (float*)(wsI + off); off += CO * KW * Hd;

    // 1. set deg_i/cnt to -1, bstart to -1 sentinel (one DMA memset)
    hipMemsetAsync(deg_i, 0xFF, (size_t)(Nn + Nn + 132) * 4, stream);
    // 2. degree histogram + batch starts + W pack (one dispatch)
    countpack_kernel<<<(Ee + 255) / 256, 256, 0, stream>>>(ei, batch, deg_i, bstart,
        conv_w, wT2, W0, W1, W2, Bph, Bpm, Bpl);
    // 3. single-dispatch scan: direct offset sum + local scan + dinv + bstart fix
    scanBC2_kernel<<<SCB, 256, 0, stream>>>(deg_i, row_ptr, dinv, bstart);
    // 4. layer-0 matmul merged with CSR fill (independent work)
    dim3 aggGrid((Nn + 3) / 4);
    mmxfill_kernel<<<MMB + (Ee + 255) / 256, 256, 0, stream>>>(x, Bph, Bpm, Bpl,
        dinv, hw, ei, row_ptr, cnt, csr_src);
    agg_kernel<<<aggGrid, 256, 0, stream>>>(hw, row_ptr, csr_src, dinv, b0, hbuf);
    // 5. layers 1,2
    mmx_kernel<<<MMB, 256, 0, stream>>>(hbuf, Bph + 16384, Bpm + 16384, Bpl + 16384, dinv, hw);
    agg_kernel<<<aggGrid, 256, 0, stream>>>(hw, row_ptr, csr_src, dinv, b1, hbuf);
    mmx_kernel<<<MMB, 256, 0, stream>>>(hbuf, Bph + 32768, Bpm + 32768, Bpl + 32768, dinv, hw);
    agg_kernel<<<aggGrid, 256, 0, stream>>>(hw, row_ptr, csr_src, dinv, b2, hbuf);
    // 6. fused tail: rank-topk + conv + lin1 + lin2 (one dispatch)
    tail_kernel<<<Bg, 1024, 0, stream>>>(hbuf, bstart, wT2, conv_b,
                                         l1w, l1b, l2w, l2b, out);
}